// Round 1
// baseline (285.209 us; speedup 1.0000x reference)
//
#include <hip/hip_runtime.h>

#define KE_KCAL 332.0637f
#define R_ON_C 2.5f
#define R_OFF_C 7.5f

constexpr int N_ATOMS = 6144;
constexpr int FEAT = 128;
constexpr int TJ = 128;               // pair-tile size
constexpr int NT = N_ATOMS / TJ;      // 48 tiles

// ---------------- kernel A: pred_charge[i] = f[i]·w + z_table[z[i]] ----------
// one 64-lane wave per atom; lane l covers features l and l+64.
__global__ __launch_bounds__(256) void pred_kernel(
    const float* __restrict__ f, const int* __restrict__ z,
    const float* __restrict__ w, const float* __restrict__ ztab,
    float* __restrict__ pred, float* __restrict__ qsum)
{
    int gid  = blockIdx.x * blockDim.x + threadIdx.x;
    int atom = gid >> 6;
    int lane = threadIdx.x & 63;
    if (atom >= N_ATOMS) return;

    const float* frow = f + (size_t)atom * FEAT;
    float p = frow[lane] * w[lane] + frow[lane + 64] * w[lane + 64];
    #pragma unroll
    for (int off = 32; off > 0; off >>= 1)
        p += __shfl_down(p, off, 64);

    if (lane == 0) {
        p += ztab[z[atom]];
        pred[atom] = p;
        atomicAdd(qsum, p);
    }
}

// ---------------- kernel B: q[i] = pred[i] + correction -> d_out[1..] --------
__global__ __launch_bounds__(256) void qfin_kernel(
    const float* __restrict__ pred, const float* __restrict__ qsum,
    const float* __restrict__ total_charge, float* __restrict__ qout)
{
    int i = blockIdx.x * blockDim.x + threadIdx.x;
    if (i >= N_ATOMS) return;
    float corr = (total_charge[0] - qsum[0]) / (float)N_ATOMS;
    qout[i] = pred[i] + corr;
}

// ---------------- kernel C: pairwise energy ---------------------------------
// grid (NT, NT); block handles i-tile bi vs j-tile bj, upper triangle only.
__global__ __launch_bounds__(TJ) void pair_kernel(
    const float* __restrict__ xyz, const float* __restrict__ q,
    float* __restrict__ eacc)
{
    int bi = blockIdx.x, bj = blockIdx.y;
    if (bj < bi) return;   // uniform early exit, before any barrier

    __shared__ float sx[TJ], sy[TJ], sz[TJ], shq[TJ], ssq[TJ];
    int t = threadIdx.x;

    int j = bj * TJ + t;
    float xj = xyz[3*j], yj = xyz[3*j+1], zj = xyz[3*j+2];
    sx[t] = xj; sy[t] = yj; sz[t] = zj;
    shq[t] = q[j];
    ssq[t] = xj*xj + yj*yj + zj*zj;
    __syncthreads();

    int i = bi * TJ + t;
    float xi = xyz[3*i], yi = xyz[3*i+1], zi = xyz[3*i+2];
    float qi = q[i];
    float sqi = xi*xi + yi*yi + zi*zi;

    float acc = 0.f;
    for (int jj = 0; jj < TJ; ++jj) {
        int gj = bj * TJ + jj;
        float r2 = sqi + ssq[jj] - 2.f * (xi*sx[jj] + yi*sy[jj] + zi*sz[jj]);
        r2 = fmaxf(r2, 0.f);
        bool m = (gj > i) && (r2 > 0.f);
        float r2s = m ? r2 : 1.f;
        float r = sqrtf(r2s);
        // f_switch(r): arg = (r - R_ON)/(R_OFF - R_ON)
        float arg = (r - R_ON_C) / (R_OFF_C - R_ON_C);
        float omx = 1.f - arg;
        float su = (omx > 0.f) ? expf(-1.f / omx) : 0.f;  // sigma(1-arg)
        float sd = (arg > 0.f) ? expf(-1.f / arg) : 0.f;  // sigma(arg)
        float fs = su / (su + sd);
        float term = fs / sqrtf(r2s + 1.f) + (1.f - fs) / r;
        acc += m ? qi * shq[jj] * term : 0.f;
    }

    // block reduction: wave shuffle then 2-way LDS combine
    #pragma unroll
    for (int off = 32; off > 0; off >>= 1)
        acc += __shfl_down(acc, off, 64);

    __shared__ float wacc[TJ / 64];
    if ((t & 63) == 0) wacc[t >> 6] = acc;
    __syncthreads();
    if (t == 0) {
        float s = 0.f;
        #pragma unroll
        for (int wv = 0; wv < TJ / 64; ++wv) s += wacc[wv];
        atomicAdd(eacc, s);
    }
}

// ---------------- kernel D: finalize energy ---------------------------------
__global__ void efin_kernel(const float* __restrict__ eacc, float* __restrict__ out0)
{
    if (threadIdx.x == 0 && blockIdx.x == 0)
        out0[0] = KE_KCAL * eacc[0];
}

extern "C" void kernel_launch(void* const* d_in, const int* in_sizes, int n_in,
                              void* d_out, int out_size, void* d_ws, size_t ws_size,
                              hipStream_t stream) {
    const float* f    = (const float*)d_in[0];
    const int*   z    = (const int*)  d_in[1];
    const float* xyz  = (const float*)d_in[2];
    const float* qtot = (const float*)d_in[3];
    const float* w    = (const float*)d_in[4];
    const float* ztab = (const float*)d_in[5];
    float* out = (float*)d_out;           // out[0] = energy, out[1..N] = q

    float* ws   = (float*)d_ws;
    float* eacc = ws + 0;                 // energy accumulator
    float* qsum = ws + 1;                 // sum of pred_charge
    float* pred = ws + 2;                 // N_ATOMS floats

    // zero the two accumulators (ws is re-poisoned to 0xAA every call)
    hipMemsetAsync(d_ws, 0, 2 * sizeof(float), stream);

    // A: pred_charge + global sum (wave per atom)
    {
        int threads = 256;
        int blocks  = (N_ATOMS * 64) / threads;
        pred_kernel<<<blocks, threads, 0, stream>>>(f, z, w, ztab, pred, qsum);
    }
    // B: q = pred + correction  -> out[1..]
    {
        int threads = 256;
        int blocks  = (N_ATOMS + threads - 1) / threads;
        qfin_kernel<<<blocks, threads, 0, stream>>>(pred, qsum, qtot, out + 1);
    }
    // C: pairwise energy (triangular tiles)
    {
        dim3 grid(NT, NT);
        pair_kernel<<<grid, TJ, 0, stream>>>(xyz, out + 1, eacc);
    }
    // D: energy finalize
    efin_kernel<<<1, 64, 0, stream>>>(eacc, out);
}

// Round 2
// 113.017 us; speedup vs baseline: 2.5236x; 2.5236x over previous
//
#include <hip/hip_runtime.h>

#define KE_KCAL 332.0637f

constexpr int N_ATOMS = 6144;
constexpr int FEAT = 128;
constexpr int TJ = 64;                    // one wave per tile-pair
constexpr int NT = N_ATOMS / TJ;          // 96
constexpr int NTRI = NT * (NT + 1) / 2;   // 4656 triangular blocks
constexpr int NEPART = 64;                // spread energy accumulators

// ---------------- kernel A: pred[i] = f[i]·w + z_table[z[i]] ----------------
// one 64-lane wave per atom; lane l covers features l and l+64.
__global__ __launch_bounds__(256) void pred_kernel(
    const float* __restrict__ f, const int* __restrict__ z,
    const float* __restrict__ w, const float* __restrict__ ztab,
    float* __restrict__ pred)
{
    int gid  = blockIdx.x * blockDim.x + threadIdx.x;
    int atom = gid >> 6;
    int lane = threadIdx.x & 63;
    if (atom >= N_ATOMS) return;

    const float* frow = f + (size_t)atom * FEAT;
    float p = frow[lane] * w[lane] + frow[lane + 64] * w[lane + 64];
    #pragma unroll
    for (int off = 32; off > 0; off >>= 1)
        p += __shfl_down(p, off, 64);

    if (lane == 0) pred[atom] = p + ztab[z[atom]];
}

// ---------------- kernel B: qsum = sum(pred), single block ------------------
__global__ __launch_bounds__(256) void sum_kernel(
    const float* __restrict__ pred, float* __restrict__ qsum)
{
    int t = threadIdx.x;
    float s = 0.f;
    for (int i = t; i < N_ATOMS; i += 256) s += pred[i];
    #pragma unroll
    for (int off = 32; off > 0; off >>= 1)
        s += __shfl_down(s, off, 64);
    __shared__ float wacc[4];
    if ((t & 63) == 0) wacc[t >> 6] = s;
    __syncthreads();
    if (t == 0) qsum[0] = wacc[0] + wacc[1] + wacc[2] + wacc[3];
}

// ---------------- kernel C: q -> d_out[1..], pack xq = {x,y,z,q} ------------
__global__ __launch_bounds__(256) void qfin_kernel(
    const float* __restrict__ pred, const float* __restrict__ qsum,
    const float* __restrict__ total_charge, const float* __restrict__ xyz,
    float* __restrict__ qout, float4* __restrict__ xq)
{
    int i = blockIdx.x * blockDim.x + threadIdx.x;
    if (i >= N_ATOMS) return;
    float corr = (total_charge[0] - qsum[0]) * (1.0f / (float)N_ATOMS);
    float q = pred[i] + corr;
    qout[i] = q;
    xq[i] = make_float4(xyz[3*i], xyz[3*i+1], xyz[3*i+2], q);
}

// ---------------- kernel D: pairwise energy ---------------------------------
// 1D triangular grid: block lin -> (bi, bj), bi <= bj. One 64-lane wave per
// 64x64 tile-pair. J-atom data is wave-uniform -> scalar loads; no LDS, no
// barriers. Branchless switch function via native transcendentals:
//   fs = 1/(1+exp(1/omx - 1/arg)), clamped args reproduce both saturations.
__global__ __launch_bounds__(64) void pair_kernel(
    const float4* __restrict__ xq, float* __restrict__ epart)
{
    int lin = blockIdx.x;
    // decode triangular index (NT=96): off(bi) = bi*NT - bi*(bi-1)/2
    int bi = (int)((2.0f * NT + 1.0f
                    - __builtin_amdgcn_sqrtf((float)((2*NT+1)*(2*NT+1) - 8*lin))) * 0.5f);
    int off = bi * NT - ((bi * (bi - 1)) >> 1);
    if (lin < off) { --bi; off = bi * NT - ((bi * (bi - 1)) >> 1); }
    else {
        int nxt = (bi + 1) * NT - (((bi + 1) * bi) >> 1);
        if (lin >= nxt) { ++bi; off = nxt; }
    }
    int bj = bi + (lin - off);

    int lane = threadIdx.x;
    int i = bi * TJ + lane;
    float4 pi = xq[i];
    int gj0 = bj * TJ;

    float acc = 0.f;
    #pragma unroll 4
    for (int jj = 0; jj < TJ; ++jj) {
        float4 pj = xq[gj0 + jj];            // uniform address -> s_load
        float dx = pi.x - pj.x, dy = pi.y - pj.y, dz = pi.z - pj.z;
        float r2 = dx*dx + dy*dy + dz*dz;
        bool m = ((gj0 + jj) > i) && (r2 > 0.f);
        float r2s = m ? r2 : 1.0f;
        float qq  = m ? pi.w * pj.w : 0.f;

        float r   = __builtin_amdgcn_sqrtf(r2s);
        float arg = fmaf(r, 0.2f, -0.5f);                 // (r - 2.5)/5
        float ac  = fmaxf(arg, 1e-20f);
        float oc  = fmaxf(1.f - arg, 1e-20f);
        float d   = __builtin_amdgcn_rcpf(oc) - __builtin_amdgcn_rcpf(ac);
        float e   = __expf(d);                             // native v_exp
        float fs  = __builtin_amdgcn_rcpf(1.f + e);
        float t2  = __builtin_amdgcn_rsqf(r2s);            // 1/r
        float t1  = __builtin_amdgcn_rsqf(r2s + 1.f);      // 1/sqrt(r2+1)
        float term = fmaf(fs, t1 - t2, t2);
        acc = fmaf(qq, term, acc);
    }

    #pragma unroll
    for (int off2 = 32; off2 > 0; off2 >>= 1)
        acc += __shfl_down(acc, off2, 64);
    if (lane == 0) atomicAdd(&epart[blockIdx.x & (NEPART - 1)], acc);
}

// ---------------- kernel E: finalize energy ---------------------------------
__global__ __launch_bounds__(64) void efin_kernel(
    const float* __restrict__ epart, float* __restrict__ out0)
{
    int lane = threadIdx.x;
    float s = epart[lane];
    #pragma unroll
    for (int off = 32; off > 0; off >>= 1)
        s += __shfl_down(s, off, 64);
    if (lane == 0) out0[0] = KE_KCAL * s;
}

extern "C" void kernel_launch(void* const* d_in, const int* in_sizes, int n_in,
                              void* d_out, int out_size, void* d_ws, size_t ws_size,
                              hipStream_t stream) {
    const float* f    = (const float*)d_in[0];
    const int*   z    = (const int*)  d_in[1];
    const float* xyz  = (const float*)d_in[2];
    const float* qtot = (const float*)d_in[3];
    const float* w    = (const float*)d_in[4];
    const float* ztab = (const float*)d_in[5];
    float* out = (float*)d_out;            // out[0] = energy, out[1..N] = q

    // workspace layout (bytes):
    //   [0 .. 255]        epart[64]
    //   [256 .. 259]      qsum
    //   [512 .. 512+98303] xq[N] float4 (16B aligned)
    //   [98816 ..]        pred[N]
    char* wsb = (char*)d_ws;
    float*  epart = (float*)(wsb + 0);
    float*  qsum  = (float*)(wsb + 256);
    float4* xq    = (float4*)(wsb + 512);
    float*  pred  = (float*)(wsb + 512 + N_ATOMS * sizeof(float4));

    // zero accumulators (ws re-poisoned to 0xAA each call)
    hipMemsetAsync(d_ws, 0, 512, stream);

    pred_kernel<<<(N_ATOMS * 64) / 256, 256, 0, stream>>>(f, z, w, ztab, pred);
    sum_kernel<<<1, 256, 0, stream>>>(pred, qsum);
    qfin_kernel<<<(N_ATOMS + 255) / 256, 256, 0, stream>>>(pred, qsum, qtot, xyz, out + 1, xq);
    pair_kernel<<<NTRI, TJ, 0, stream>>>(xq, epart);
    efin_kernel<<<1, 64, 0, stream>>>(epart, out);
}